// Round 4
// baseline (3545.191 us; speedup 1.0000x reference)
//
#include <hip/hip_runtime.h>
#include <hip/hip_bf16.h>

#define NB 64      // batch
#define NS 40      // src len
#define NT 39      // tgt steps (T-1)
#define NE 256     // emb
#define NU 1024    // hidden
#define G3 3072    // 3*U
#define NVO 8192

typedef __attribute__((ext_vector_type(8))) short short8_t;   // 8 x bf16 frag
typedef __attribute__((ext_vector_type(4))) float float4_t;   // 4 x f32 acc

// plane offsets (ushort counts)
#define PO_S  3145728   // step weights: 64 blk * 96 * 64 * 8
#define PO_GX 786432    // gx weights: 192 * 8 * 64 * 8
#define PO_FC 8388608   // fc weights: 512 * 32 * 64 * 8

// ---------------------------------------------------------------------------
__device__ __forceinline__ unsigned short f2bf(float x) {
    union { float f; unsigned u; } v; v.f = x;
    unsigned r = v.u + 0x7fffu + ((v.u >> 16) & 1u);
    return (unsigned short)(r >> 16);
}
__device__ __forceinline__ float bf2f(unsigned short h) {
    union { float f; unsigned u; } v; v.u = ((unsigned)h) << 16; return v.f;
}
__device__ __forceinline__ float sigmoidf_(float x) { return 1.0f / (1.0f + expf(-x)); }

// Device-scope grid barrier. All 64 blocks are co-resident (64 <= 256 CUs,
// LDS 48KB, VGPR capped 128 via launch_bounds), so spinning is safe.
// target must be gridDim.x * (number of barriers so far) — monotonic, no reset.
__device__ __forceinline__ void grid_bar(unsigned* cnt, unsigned target) {
    __syncthreads();
    if (threadIdx.x == 0) {
        __hip_atomic_fetch_add(cnt, 1u, __ATOMIC_ACQ_REL, __HIP_MEMORY_SCOPE_AGENT);
        unsigned v;
        do {
            __builtin_amdgcn_s_sleep(2);
            v = __hip_atomic_load(cnt, __ATOMIC_ACQUIRE, __HIP_MEMORY_SCOPE_AGENT);
        } while (v < target);
    }
    __syncthreads();
}

// ---------------------------------------------------------------------------
// Generic packer: K x N fp32 -> MFMA B-frag order hi/lo. grid (N/16, K/32).
// ---------------------------------------------------------------------------
__global__ __launch_bounds__(64) void k_pack_b(const float* __restrict__ W, int N,
                                               unsigned short* __restrict__ Bp, int planeOff)
{
    int nt = blockIdx.x, s = blockIdx.y;
    int l = threadIdx.x;
    int n = nt * 16 + (l & 15);
    int k0 = s * 32 + (l >> 4) * 8;
    size_t ob = (((size_t)nt * gridDim.y + s) * 64 + l) * 8;
#pragma unroll
    for (int jj = 0; jj < 8; ++jj) {
        float x = W[(size_t)(k0 + jj) * N + n];
        unsigned short h = f2bf(x);
        Bp[ob + jj] = h;
        Bp[planeOff + ob + jj] = f2bf(x - bf2f(h));
    }
}

// Step-weight packer: scan block j owns cols {g*1024 + 16j..+16}. grid (64, 96).
__global__ __launch_bounds__(64) void k_pack_step(const float* __restrict__ W,
                                                  unsigned short* __restrict__ Bp)
{
    int j = blockIdx.x;
    int q = blockIdx.y;            // g*32 + s
    int g = q >> 5, s = q & 31;
    int l = threadIdx.x;
    int n = g * NU + j * 16 + (l & 15);
    int k0 = s * 32 + (l >> 4) * 8;
    size_t ob = (((size_t)j * 96 + q) * 64 + l) * 8;
#pragma unroll
    for (int jj = 0; jj < 8; ++jj) {
        float x = W[(size_t)(k0 + jj) * G3 + n];
        unsigned short h = f2bf(x);
        Bp[ob + jj] = h;
        Bp[PO_S + ob + jj] = f2bf(x - bf2f(h));
    }
}

// Gather embeddings -> bf16 plane. grid (rows), block 256 (= NE).
__global__ __launch_bounds__(256) void k_gather(const int* __restrict__ idx,
                                                int cols_total, int cols_used,
                                                const float* __restrict__ emb,
                                                unsigned short* __restrict__ Ax)
{
    int row = blockIdx.x;
    int b = row / cols_used, c = row - b * cols_used;
    int tok = idx[b * cols_total + c];
    int k = threadIdx.x;
    Ax[(size_t)row * NE + k] = f2bf(emb[(size_t)tok * NE + k]);
}

// GX GEMM: out[row][col] = Ax[row][:256] @ W + bias. grid (M/64, 48), block 256.
__global__ __launch_bounds__(256) void k_gx_mfma(const unsigned short* __restrict__ Ax,
                                                 const unsigned short* __restrict__ Bp,
                                                 const float* __restrict__ bias,
                                                 float* __restrict__ out)
{
    int tx = threadIdx.x;
    int w = tx >> 6, l = tx & 63;
    int lq = l >> 4, lr = l & 15;
    int row0 = blockIdx.x * 64 + w * 16;
    int cb = blockIdx.y;
    float4_t acc[4] = {{0,0,0,0},{0,0,0,0},{0,0,0,0},{0,0,0,0}};
    const unsigned short* Ab = Ax + (size_t)(row0 + lr) * NE + lq * 8;
#pragma unroll
    for (int s = 0; s < 8; ++s) {
        short8_t ah = *(const short8_t*)(Ab + s * 32);
#pragma unroll
        for (int nf = 0; nf < 4; ++nf) {
            const unsigned short* bp = Bp + ((((size_t)cb * 4 + nf) * 8 + s) * 64 + l) * 8;
            short8_t bh = *(const short8_t*)bp;
            short8_t bl = *(const short8_t*)(bp + PO_GX);
            acc[nf] = __builtin_amdgcn_mfma_f32_16x16x32_bf16(ah, bh, acc[nf], 0, 0, 0);
            acc[nf] = __builtin_amdgcn_mfma_f32_16x16x32_bf16(ah, bl, acc[nf], 0, 0, 0);
        }
    }
#pragma unroll
    for (int nf = 0; nf < 4; ++nf) {
        int col = cb * 64 + nf * 16 + lr;
        float bi = bias[col];
#pragma unroll
        for (int r = 0; r < 4; ++r) {
            int gr = row0 + lq * 4 + r;
            out[(size_t)gr * G3 + col] = acc[nf][r] + bi;
        }
    }
}

// ---------------------------------------------------------------------------
// Persistent encoder scan: 64 blocks x 1024 thr, one block per 16-col triple.
// Loops all 40 steps with a device-scope grid barrier between steps; ends by
// computing the attention ctx for decoder t=0 (block = batch).
// ---------------------------------------------------------------------------
__global__ __launch_bounds__(1024, 4) void k_enc_scan(
    const unsigned short* __restrict__ Bp,
    const float* __restrict__ GX, const float* __restrict__ b1,
    unsigned short* h_hi0, unsigned short* h_lo0,
    unsigned short* h_hi1, unsigned short* h_lo1,
    float* enc_out,
    unsigned short* ctx_hi, unsigned short* ctx_lo,
    unsigned* cnt)
{
    __shared__ float red[4][4][3][256];        // 48 KB; reused for attention
    int tx = threadIdx.x;
    int j = blockIdx.x;
    int w = tx >> 6, l = tx & 63;
    int lq = l >> 4, lr = l & 15;
    int mw = w & 3, kw = w >> 2;
    const unsigned short* Bb = Bp + (size_t)j * 96 * 512 + l * 8;
    unsigned bt = 0;

#pragma unroll 1
    for (int t = 0; t < NS; ++t) {
        const unsigned short* Ah = (t & 1) ? h_hi1 : h_hi0;
        const unsigned short* Al = (t & 1) ? h_lo1 : h_lo0;
        unsigned short* Oh = (t & 1) ? h_hi0 : h_hi1;
        unsigned short* Ol = (t & 1) ? h_lo0 : h_lo1;
        float4_t acc[3] = {{0,0,0,0},{0,0,0,0},{0,0,0,0}};
        const unsigned short* Ab  = Ah + (size_t)(mw * 16 + lr) * NU + kw * 256 + lq * 8;
        const unsigned short* Alb = Al + (size_t)(mw * 16 + lr) * NU + kw * 256 + lq * 8;
#pragma unroll
        for (int sl = 0; sl < 8; ++sl) {
            int sg = kw * 8 + sl;
            short8_t ah = *(const short8_t*)(Ab + sl * 32);
            short8_t al = *(const short8_t*)(Alb + sl * 32);
#pragma unroll
            for (int g = 0; g < 3; ++g) {
                const unsigned short* bp = Bb + (size_t)(g * 32 + sg) * 512;
                short8_t bh = *(const short8_t*)bp;
                short8_t bl = *(const short8_t*)(bp + PO_S);
                acc[g] = __builtin_amdgcn_mfma_f32_16x16x32_bf16(ah, bh, acc[g], 0, 0, 0);
                acc[g] = __builtin_amdgcn_mfma_f32_16x16x32_bf16(ah, bl, acc[g], 0, 0, 0);
                acc[g] = __builtin_amdgcn_mfma_f32_16x16x32_bf16(al, bh, acc[g], 0, 0, 0);
            }
        }
#pragma unroll
        for (int g = 0; g < 3; ++g)
#pragma unroll
            for (int r = 0; r < 4; ++r)
                red[kw][mw][g][(lq * 4 + r) * 16 + lr] = acc[g][r];
        __syncthreads();
        // epilogue: 1024 threads = 64 rows x 16 cols
        int b = tx >> 4, c = tx & 15;
        int mw2 = b >> 4, ml = b & 15;
        float gz = 0.f, gr_ = 0.f, gc = 0.f;
#pragma unroll
        for (int k2 = 0; k2 < 4; ++k2) {
            gz  += red[k2][mw2][0][ml * 16 + c];
            gr_ += red[k2][mw2][1][ml * 16 + c];
            gc  += red[k2][mw2][2][ml * 16 + c];
        }
        int col = j * 16 + c;
        const float* gx = GX + ((size_t)b * NS + t) * G3 + col;
        float z = sigmoidf_(gx[0]  + gz  + b1[col]);
        float r = sigmoidf_(gx[NU] + gr_ + b1[NU + col]);
        float cc = tanhf(gx[2 * NU] + r * (gc + b1[2 * NU + col]));
        float hp = bf2f(Ah[(size_t)b * NU + col]) + bf2f(Al[(size_t)b * NU + col]);
        float hn = z * hp + (1.f - z) * cc;
        enc_out[(size_t)b * NS * NU + (size_t)t * NU + col] = hn;
        unsigned short hh = f2bf(hn);
        Oh[(size_t)b * NU + col] = hh;
        Ol[(size_t)b * NU + col] = f2bf(hn - bf2f(hh));
        bt += 64;
        grid_bar(cnt, bt);
    }

    // ---- attention for decoder t=0: block = batch ----
    float* h_sh  = (float*)red;
    float* sc_sh = (float*)red + 1056;
    int b = j;
    const float* eb = enc_out + (size_t)b * NS * NU;
    h_sh[tx] = eb[(size_t)(NS - 1) * NU + tx];
    __syncthreads();
    for (int s = w; s < NS; s += 16) {
        float p = 0.f;
        for (int k = l; k < NU; k += 64) p += h_sh[k] * eb[(size_t)s * NU + k];
        for (int off = 32; off > 0; off >>= 1) p += __shfl_down(p, off);
        if (l == 0) sc_sh[s] = p;
    }
    __syncthreads();
    if (w == 0) {
        float v = (l < NS) ? sc_sh[l] : -3.0e38f;
        float m = v;
        for (int off = 32; off > 0; off >>= 1) m = fmaxf(m, __shfl_down(m, off));
        m = __shfl(m, 0);
        float e = (l < NS) ? expf(v - m) : 0.f;
        float ss = e;
        for (int off = 32; off > 0; off >>= 1) ss += __shfl_down(ss, off);
        ss = __shfl(ss, 0);
        if (l < NS) sc_sh[l] = e / ss;
    }
    __syncthreads();
    float c = 0.f;
#pragma unroll 8
    for (int s = 0; s < NS; ++s) c += sc_sh[s] * eb[(size_t)s * NU + tx];
    unsigned short h = f2bf(c);
    ctx_hi[(size_t)b * NU + tx] = h;
    ctx_lo[(size_t)b * NU + tx] = f2bf(c - bf2f(h));
}

// ---------------------------------------------------------------------------
// Persistent decoder scan: per t: [GEMM+gates from ctx; bar; attention; bar].
// ctx / hdec are read+written across barriers — no __restrict on them.
// ---------------------------------------------------------------------------
__global__ __launch_bounds__(1024, 4) void k_dec_scan(
    const unsigned short* __restrict__ Bp,
    const float* __restrict__ GX, const float* __restrict__ b1,
    unsigned short* ctx_hi, unsigned short* ctx_lo,
    const float* __restrict__ enc_out,
    float* hdec,
    unsigned short* __restrict__ Hs_hi, unsigned short* __restrict__ Hs_lo,
    unsigned* cnt)
{
    __shared__ float red[4][4][3][256];
    int tx = threadIdx.x;
    int j = blockIdx.x;
    int w = tx >> 6, l = tx & 63;
    int lq = l >> 4, lr = l & 15;
    int mw = w & 3, kw = w >> 2;
    const unsigned short* Bb = Bp + (size_t)j * 96 * 512 + l * 8;
    unsigned bt = 0;

#pragma unroll 1
    for (int t = 0; t < NT; ++t) {
        // ---- phase A: GEMM + gates ----
        float4_t acc[3] = {{0,0,0,0},{0,0,0,0},{0,0,0,0}};
        const unsigned short* Ab  = ctx_hi + (size_t)(mw * 16 + lr) * NU + kw * 256 + lq * 8;
        const unsigned short* Alb = ctx_lo + (size_t)(mw * 16 + lr) * NU + kw * 256 + lq * 8;
#pragma unroll
        for (int sl = 0; sl < 8; ++sl) {
            int sg = kw * 8 + sl;
            short8_t ah = *(const short8_t*)(Ab + sl * 32);
            short8_t al = *(const short8_t*)(Alb + sl * 32);
#pragma unroll
            for (int g = 0; g < 3; ++g) {
                const unsigned short* bp = Bb + (size_t)(g * 32 + sg) * 512;
                short8_t bh = *(const short8_t*)bp;
                short8_t bl = *(const short8_t*)(bp + PO_S);
                acc[g] = __builtin_amdgcn_mfma_f32_16x16x32_bf16(ah, bh, acc[g], 0, 0, 0);
                acc[g] = __builtin_amdgcn_mfma_f32_16x16x32_bf16(ah, bl, acc[g], 0, 0, 0);
                acc[g] = __builtin_amdgcn_mfma_f32_16x16x32_bf16(al, bh, acc[g], 0, 0, 0);
            }
        }
#pragma unroll
        for (int g = 0; g < 3; ++g)
#pragma unroll
            for (int r = 0; r < 4; ++r)
                red[kw][mw][g][(lq * 4 + r) * 16 + lr] = acc[g][r];
        __syncthreads();
        int b = tx >> 4, c = tx & 15;
        int mw2 = b >> 4, ml = b & 15;
        float gz = 0.f, gr_ = 0.f, gc = 0.f;
#pragma unroll
        for (int k2 = 0; k2 < 4; ++k2) {
            gz  += red[k2][mw2][0][ml * 16 + c];
            gr_ += red[k2][mw2][1][ml * 16 + c];
            gc  += red[k2][mw2][2][ml * 16 + c];
        }
        int col = j * 16 + c;
        const float* gx = GX + ((size_t)b * NT + t) * G3 + col;
        float z = sigmoidf_(gx[0]  + gz  + b1[col]);
        float r = sigmoidf_(gx[NU] + gr_ + b1[NU + col]);
        float cc = tanhf(gx[2 * NU] + gc + r * b1[2 * NU + col]);
        float hn = (1.f - z) * cc;
        hdec[(size_t)b * NU + col] = hn;
        size_t row = (size_t)t * NB + b;
        unsigned short hh = f2bf(hn);
        Hs_hi[row * NU + col] = hh;
        Hs_lo[row * NU + col] = f2bf(hn - bf2f(hh));
        bt += 64;
        grid_bar(cnt, bt);

        // ---- phase B: attention for next step (block = batch) ----
        if (t < NT - 1) {
            float* h_sh  = (float*)red;
            float* sc_sh = (float*)red + 1056;
            int bb = j;
            const float* eb = enc_out + (size_t)bb * NS * NU;
            h_sh[tx] = hdec[(size_t)bb * NU + tx];
            __syncthreads();
            for (int s = w; s < NS; s += 16) {
                float p = 0.f;
                for (int k = l; k < NU; k += 64) p += h_sh[k] * eb[(size_t)s * NU + k];
                for (int off = 32; off > 0; off >>= 1) p += __shfl_down(p, off);
                if (l == 0) sc_sh[s] = p;
            }
            __syncthreads();
            if (w == 0) {
                float v = (l < NS) ? sc_sh[l] : -3.0e38f;
                float m = v;
                for (int off = 32; off > 0; off >>= 1) m = fmaxf(m, __shfl_down(m, off));
                m = __shfl(m, 0);
                float e = (l < NS) ? expf(v - m) : 0.f;
                float ss = e;
                for (int off = 32; off > 0; off >>= 1) ss += __shfl_down(ss, off);
                ss = __shfl(ss, 0);
                if (l < NS) sc_sh[l] = e / ss;
            }
            __syncthreads();
            float cx = 0.f;
#pragma unroll 8
            for (int s = 0; s < NS; ++s) cx += sc_sh[s] * eb[(size_t)s * NU + tx];
            unsigned short h = f2bf(cx);
            ctx_hi[(size_t)bb * NU + tx] = h;
            ctx_lo[(size_t)bb * NU + tx] = f2bf(cx - bf2f(h));
            bt += 64;
            grid_bar(cnt, bt);
        }
    }
}

// ---------------------------------------------------------------------------
// FC: grid (10 M-tiles of 256, 128 n-blocks of 64). Wave = 64 rows x 64 cols.
// ---------------------------------------------------------------------------
__global__ __launch_bounds__(256) void k_fc_mfma(const unsigned short* __restrict__ Ah,
                                                 const unsigned short* __restrict__ Al,
                                                 const unsigned short* __restrict__ Bp,
                                                 const float* __restrict__ bias,
                                                 float* __restrict__ out)
{
    int tx = threadIdx.x;
    int w = tx >> 6, l = tx & 63;
    int lq = l >> 4, lr = l & 15;
    int row0 = blockIdx.x * 256 + w * 64;
    int cb = blockIdx.y;
    float4_t acc[4][4];
#pragma unroll
    for (int i = 0; i < 4; ++i)
#pragma unroll
        for (int jn = 0; jn < 4; ++jn) acc[i][jn] = (float4_t){0.f, 0.f, 0.f, 0.f};
#pragma unroll 1
    for (int s = 0; s < NU / 32; ++s) {
        short8_t ah[4], al[4];
#pragma unroll
        for (int mf = 0; mf < 4; ++mf) {
            const unsigned short* ap = Ah + (size_t)(row0 + mf * 16 + lr) * NU + s * 32 + lq * 8;
            const unsigned short* alp = Al + (size_t)(row0 + mf * 16 + lr) * NU + s * 32 + lq * 8;
            ah[mf] = *(const short8_t*)ap;
            al[mf] = *(const short8_t*)alp;
        }
#pragma unroll
        for (int nf = 0; nf < 4; ++nf) {
            const unsigned short* bp = Bp + ((((size_t)cb * 4 + nf) * 32 + s) * 64 + l) * 8;
            short8_t bh = *(const short8_t*)bp;
            short8_t bl = *(const short8_t*)(bp + PO_FC);
#pragma unroll
            for (int mf = 0; mf < 4; ++mf) {
                acc[mf][nf] = __builtin_amdgcn_mfma_f32_16x16x32_bf16(ah[mf], bh, acc[mf][nf], 0, 0, 0);
                acc[mf][nf] = __builtin_amdgcn_mfma_f32_16x16x32_bf16(ah[mf], bl, acc[mf][nf], 0, 0, 0);
                acc[mf][nf] = __builtin_amdgcn_mfma_f32_16x16x32_bf16(al[mf], bh, acc[mf][nf], 0, 0, 0);
            }
        }
    }
#pragma unroll
    for (int nf = 0; nf < 4; ++nf) {
        int v = cb * 64 + nf * 16 + lr;
        float bi = bias[v];
#pragma unroll
        for (int mf = 0; mf < 4; ++mf)
#pragma unroll
            for (int r = 0; r < 4; ++r) {
                int gr = row0 + mf * 16 + lq * 4 + r;   // Hs row = t*64 + b
                if (gr < NT * NB) {
                    int tt = gr >> 6, bb = gr & 63;
                    out[((size_t)bb * NT + tt) * NVO + v] = acc[mf][nf][r] + bi;
                }
            }
    }
}

// ---------------------------------------------------------------------------

extern "C" void kernel_launch(void* const* d_in, const int* in_sizes, int n_in,
                              void* d_out, int out_size, void* d_ws, size_t ws_size,
                              hipStream_t stream)
{
    const int*   inp     = (const int*)d_in[0];
    const int*   targ    = (const int*)d_in[1];
    const float* enc_emb = (const float*)d_in[2];
    const float* enc_Wx  = (const float*)d_in[3];
    const float* enc_Wh  = (const float*)d_in[4];
    const float* enc_b   = (const float*)d_in[5];
    const float* dec_emb = (const float*)d_in[6];
    const float* dec_Wx  = (const float*)d_in[7];
    // d_in[8] = dec_Wh: unused (multiplied by h_zero == 0 in reference)
    const float* dec_b   = (const float*)d_in[9];
    const float* fc_W    = (const float*)d_in[10];
    const float* fc_b    = (const float*)d_in[11];
    float* out = (float*)d_out;

    // ---- workspace carve (~89 MB) ----
    char* p = (char*)d_ws;
    float* gx_buf = (float*)p;                   p += 33554432;  // enc gx, then dec gx
    float* enc_out = (float*)p;                  p += 10485760;  // [b][s][u] fp32
    unsigned short* h_hi0 = (unsigned short*)p;  p += 131072;
    unsigned short* h_lo0 = (unsigned short*)p;  p += 131072;
    unsigned short* h_hi1 = (unsigned short*)p;  p += 131072;
    unsigned short* h_lo1 = (unsigned short*)p;  p += 131072;
    unsigned short* ctx_hi = (unsigned short*)p; p += 131072;
    unsigned short* ctx_lo = (unsigned short*)p; p += 131072;
    float* hdec = (float*)p;                     p += 262144;
    unsigned* cnts = (unsigned*)p;               p += 256;       // [0]=enc, [32]=dec
    unsigned short* Hs_hi = (unsigned short*)p;  p += 5242880;   // 2560 rows (pad)
    unsigned short* Hs_lo = (unsigned short*)p;  p += 5242880;
    // union region (33.6 MB): scan-era buffers, later overwritten by Bp_fc
    char* ureg = p;                              p += 33554432;
    unsigned short* Bp_fc  = (unsigned short*)ureg;
    unsigned short* Bp_enc = (unsigned short*)ureg;
    unsigned short* Bp_dec = (unsigned short*)(ureg + 12582912);
    unsigned short* Bp_gx  = (unsigned short*)(ureg + 25165824);
    unsigned short* Ax     = (unsigned short*)(ureg + 28311552);

    // zero initial h planes (h_hi0+h_lo0 contiguous) and barrier counters
    hipMemsetAsync(h_hi0, 0, 262144, stream);
    hipMemsetAsync(cnts, 0, 256, stream);

    // pack recurrent weights
    k_pack_step<<<dim3(64, 96), 64, 0, stream>>>(enc_Wh, Bp_enc);
    k_pack_step<<<dim3(64, 96), 64, 0, stream>>>(dec_Wx, Bp_dec);  // rows 0..1023 (ctx part)

    // ---- encoder x-path ----
    k_pack_b<<<dim3(G3 / 16, NE / 32), 64, 0, stream>>>(enc_Wx, G3, Bp_gx, PO_GX);
    k_gather<<<NB * NS, NE, 0, stream>>>(inp, NS, NS, enc_emb, Ax);
    k_gx_mfma<<<dim3(NB * NS / 64, 48), 256, 0, stream>>>(Ax, Bp_gx, enc_b, gx_buf);

    // ---- encoder scan: ONE persistent kernel (40 steps + ctx0 attention) ----
    k_enc_scan<<<64, 1024, 0, stream>>>(Bp_enc, gx_buf, enc_b + G3,
                                        h_hi0, h_lo0, h_hi1, h_lo1,
                                        enc_out, ctx_hi, ctx_lo, cnts);

    // ---- decoder x-path (reuses gx_buf, Bp_gx, Ax) ----
    k_pack_b<<<dim3(G3 / 16, NE / 32), 64, 0, stream>>>(dec_Wx + (size_t)NU * G3, G3, Bp_gx, PO_GX);
    k_gather<<<NB * NT, NE, 0, stream>>>(targ, NS, NT, dec_emb, Ax);
    k_gx_mfma<<<dim3(NB * NT / 64, 48), 256, 0, stream>>>(Ax, Bp_gx, dec_b, gx_buf);

    // ---- decoder scan: ONE persistent kernel (39 x [gates; attention]) ----
    k_dec_scan<<<64, 1024, 0, stream>>>(Bp_dec, gx_buf, dec_b + G3,
                                        ctx_hi, ctx_lo, enc_out, hdec,
                                        Hs_hi, Hs_lo, cnts + 32);

    // ---- FC head: pack fc_W over the dead scan weights, then one GEMM ----
    k_pack_b<<<dim3(NVO / 16, NU / 32), 64, 0, stream>>>(fc_W, NVO, Bp_fc, PO_FC);
    k_fc_mfma<<<dim3(10, NVO / 64), 256, 0, stream>>>(Hs_hi, Hs_lo, Bp_fc, fc_b, out);
}